// Round 1
// baseline (575.048 us; speedup 1.0000x reference)
//
#include <hip/hip_runtime.h>

// Problem constants (setup_inputs is fixed)
#define BATCH 2
#define NTXT  2048
#define TMED  4
#define MMED  256
#define TM    (TMED * MMED)      // 1024 kv rows per batch
#define DIM   1024
#define NH    16
#define DHD   64
#define KVW   2048               // k|v concatenated width

// ---------------------------------------------------------------------------
// K1: inclusive scan of locations -> txt_time (one block per batch)
// ---------------------------------------------------------------------------
__global__ __launch_bounds__(1024) void scan_kernel(const int* __restrict__ loc,
                                                    int* __restrict__ tt) {
  __shared__ int buf[NTXT];
  const int b = blockIdx.x;
  const int tid = threadIdx.x;
  buf[tid]        = loc[b * NTXT + tid];
  buf[tid + 1024] = loc[b * NTXT + tid + 1024];
  __syncthreads();
  for (int off = 1; off < NTXT; off <<= 1) {
    int a0 = (tid >= off) ? buf[tid - off] : 0;
    int a1 = buf[tid + 1024 - off];   // tid+1024-off >= 0 since off <= 1024
    __syncthreads();
    buf[tid] += a0;
    buf[tid + 1024] += a1;
    __syncthreads();
  }
  tt[b * NTXT + tid]        = buf[tid];
  tt[b * NTXT + tid + 1024] = buf[tid + 1024];
}

// ---------------------------------------------------------------------------
// K2: fp32 tiled GEMM  C[M,N] = A[M,K] @ B[K,N]   (64x64 tile, BK=16)
// ---------------------------------------------------------------------------
#define BM 64
#define BN 64
#define BK 16
__global__ __launch_bounds__(256) void gemm_f32_kernel(
    const float* __restrict__ A, const float* __restrict__ B,
    float* __restrict__ C, int M, int N, int K) {
  __shared__ float As[BK][BM];
  __shared__ float Bs[BK][BN];
  const int tid = threadIdx.x;
  const int tx = tid & 15;   // 16 col groups of 4
  const int ty = tid >> 4;   // 16 row groups of 4
  const int row0 = blockIdx.y * BM;
  const int col0 = blockIdx.x * BN;
  const int am = tid >> 2;          // 0..63 A-tile row
  const int ak = (tid & 3) << 2;    // 0,4,8,12 A-tile k (float4)
  const int bk = tid >> 4;          // 0..15 B-tile k
  const int bn = (tid & 15) << 2;   // 0..60 B-tile col (float4)

  float acc[4][4] = {};
  for (int k0 = 0; k0 < K; k0 += BK) {
    const float4 a4 = *reinterpret_cast<const float4*>(
        &A[(size_t)(row0 + am) * K + k0 + ak]);
    As[ak + 0][am] = a4.x; As[ak + 1][am] = a4.y;
    As[ak + 2][am] = a4.z; As[ak + 3][am] = a4.w;
    const float4 b4 = *reinterpret_cast<const float4*>(
        &B[(size_t)(k0 + bk) * N + col0 + bn]);
    *reinterpret_cast<float4*>(&Bs[bk][bn]) = b4;
    __syncthreads();
#pragma unroll
    for (int kk = 0; kk < BK; kk++) {
      float a[4], b[4];
      *(float4*)a = *(const float4*)&As[kk][ty * 4];
      *(float4*)b = *(const float4*)&Bs[kk][tx * 4];
#pragma unroll
      for (int i = 0; i < 4; i++)
#pragma unroll
        for (int j = 0; j < 4; j++) acc[i][j] += a[i] * b[j];
    }
    __syncthreads();
  }
#pragma unroll
  for (int i = 0; i < 4; i++) {
    float4 v = make_float4(acc[i][0], acc[i][1], acc[i][2], acc[i][3]);
    *reinterpret_cast<float4*>(
        &C[(size_t)(row0 + ty * 4 + i) * N + col0 + tx * 4]) = v;
  }
}

// ---------------------------------------------------------------------------
// K3: vbar[b,c] = mean over j of v[b,j,c]  (v = kv columns [1024,2048))
// ---------------------------------------------------------------------------
__global__ __launch_bounds__(256) void vbar_kernel(const float* __restrict__ kv,
                                                   float* __restrict__ vbar) {
  const int b = blockIdx.x >> 2;
  const int c = ((blockIdx.x & 3) << 8) + threadIdx.x;
  const float* p = kv + (size_t)b * TM * KVW + DIM + c;
  float s = 0.f;
  for (int j = 0; j < TM; j++) s += p[(size_t)j * KVW];
  vbar[b * DIM + c] = s * (1.0f / (float)TM);
}

// ---------------------------------------------------------------------------
// K4: obar[b,e] = vbar[b,:] @ Wo[:,e]
// ---------------------------------------------------------------------------
__global__ __launch_bounds__(256) void obar_kernel(const float* __restrict__ vbar,
                                                   const float* __restrict__ Wo,
                                                   float* __restrict__ obar) {
  const int b = blockIdx.x >> 2;
  const int e = ((blockIdx.x & 3) << 8) + threadIdx.x;
  float s = 0.f;
  for (int c = 0; c < DIM; c++) s += vbar[b * DIM + c] * Wo[(size_t)c * DIM + e];
  obar[b * DIM + e] = s;
}

// ---------------------------------------------------------------------------
// K5: routing + (rare) real attention. One block (256 thr) per (b, i).
// ---------------------------------------------------------------------------
__global__ __launch_bounds__(256) void attn_kernel(
    const float* __restrict__ text, const float* __restrict__ kv,
    const float* __restrict__ Wq, const float* __restrict__ Wo,
    const float* __restrict__ gamma, const float* __restrict__ beta,
    const int* __restrict__ tt, const float* __restrict__ obar,
    float* __restrict__ out) {
  const int tid = threadIdx.x;
  const int b = blockIdx.x >> 11;       // / NTXT
  const int i = blockIdx.x & (NTXT - 1);
  const int t = tt[b * NTXT + i];
  float* orow = out + (size_t)(b * NTXT + i) * DIM;

  if (t == 0) {                          // fully masked + zeroed
    for (int c = tid; c < DIM; c += 256) orow[c] = 0.f;
    return;
  }
  if (t > TMED) {                        // all-masked -> uniform softmax -> obar
    const float* ob = obar + b * DIM;
    for (int c = tid; c < DIM; c += 256) orow[c] = ob[c];
    return;
  }

  // ---- real attention row ----
  __shared__ float tn[DIM];
  __shared__ float qrow[DIM];
  __shared__ float oacc[DIM];
  __shared__ float red[256];
  __shared__ float pbuf[256];

  // LayerNorm of the text row
  const float* xrow = text + (size_t)(b * NTXT + i) * DIM;
  float x[4];
  float s = 0.f;
#pragma unroll
  for (int u = 0; u < 4; u++) { x[u] = xrow[tid + 256 * u]; s += x[u]; }
  red[tid] = s; __syncthreads();
  for (int st = 128; st > 0; st >>= 1) {
    if (tid < st) red[tid] += red[tid + st];
    __syncthreads();
  }
  const float mu = red[0] * (1.0f / DIM); __syncthreads();
  float vs = 0.f;
#pragma unroll
  for (int u = 0; u < 4; u++) { float d = x[u] - mu; vs += d * d; }
  red[tid] = vs; __syncthreads();
  for (int st = 128; st > 0; st >>= 1) {
    if (tid < st) red[tid] += red[tid + st];
    __syncthreads();
  }
  const float rstd = rsqrtf(red[0] * (1.0f / DIM) + 1e-5f); __syncthreads();
#pragma unroll
  for (int u = 0; u < 4; u++) {
    const int c = tid + 256 * u;
    tn[c] = (x[u] - mu) * rstd * gamma[c] + beta[c];
  }
  __syncthreads();

  // q = tn @ Wq   (thread owns 4 output dims, coalesced Wq reads)
  {
    float qa[4] = {0.f, 0.f, 0.f, 0.f};
    for (int c = 0; c < DIM; c++) {
      const float tv = tn[c];
      const float* w = Wq + (size_t)c * DIM + tid;
#pragma unroll
      for (int u = 0; u < 4; u++) qa[u] += tv * w[256 * u];
    }
#pragma unroll
    for (int u = 0; u < 4; u++) qrow[tid + 256 * u] = qa[u];
  }
  __syncthreads();

  const size_t kvrow0 = (size_t)(b * TM + (t - 1) * MMED) * KVW;
  const int d0 = tid & 63, g = tid >> 6;
  for (int h = 0; h < NH; h++) {
    // scores: thread tid <-> kv column j = tid
    const float* krow = kv + kvrow0 + (size_t)tid * KVW + h * DHD;
    float sc = 0.f;
#pragma unroll
    for (int d = 0; d < DHD; d++) sc += qrow[h * DHD + d] * krow[d];
    sc *= 0.125f;   // DH^-0.5
    // softmax over 256 valid columns
    red[tid] = sc; __syncthreads();
    for (int st = 128; st > 0; st >>= 1) {
      if (tid < st) red[tid] = fmaxf(red[tid], red[tid + st]);
      __syncthreads();
    }
    const float mx = red[0]; __syncthreads();
    const float e = __expf(sc - mx);
    red[tid] = e; __syncthreads();
    for (int st = 128; st > 0; st >>= 1) {
      if (tid < st) red[tid] += red[tid + st];
      __syncthreads();
    }
    const float inv = 1.0f / red[0]; __syncthreads();
    pbuf[tid] = e * inv; __syncthreads();
    // PV: 4 j-groups of 64, coalesced v reads across d
    const float* vbase = kv + kvrow0 + (size_t)(g * 64) * KVW + DIM + h * DHD + d0;
    float a = 0.f;
#pragma unroll 8
    for (int j = 0; j < 64; j++) a += pbuf[g * 64 + j] * vbase[(size_t)j * KVW];
    red[tid] = a; __syncthreads();
    if (tid < 64)
      oacc[h * DHD + tid] = red[tid] + red[64 + tid] + red[128 + tid] + red[192 + tid];
    __syncthreads();
  }

  // out row = oacc @ Wo
  float oa[4] = {0.f, 0.f, 0.f, 0.f};
  for (int c = 0; c < DIM; c++) {
    const float ov = oacc[c];
    const float* w = Wo + (size_t)c * DIM + tid;
#pragma unroll
    for (int u = 0; u < 4; u++) oa[u] += ov * w[256 * u];
  }
#pragma unroll
  for (int u = 0; u < 4; u++) orow[tid + 256 * u] = oa[u];
}

// ---------------------------------------------------------------------------
extern "C" void kernel_launch(void* const* d_in, const int* in_sizes, int n_in,
                              void* d_out, int out_size, void* d_ws, size_t ws_size,
                              hipStream_t stream) {
  const float* text  = (const float*)d_in[0];
  const float* image = (const float*)d_in[1];
  const int*   loc   = (const int*)d_in[2];
  const float* Wq    = (const float*)d_in[3];
  const float* Wkv   = (const float*)d_in[4];
  const float* Wo    = (const float*)d_in[5];
  const float* gamma = (const float*)d_in[6];
  const float* beta  = (const float*)d_in[7];
  float* out = (float*)d_out;

  // workspace layout: kv (2048*2048 f32 = 16 MB) | txt_time | vbar | obar
  float* kv   = (float*)d_ws;
  int*   tt   = (int*)(kv + (size_t)BATCH * TM * KVW);
  float* vbar = (float*)(tt + BATCH * NTXT);
  float* obar = vbar + BATCH * DIM;

  scan_kernel<<<BATCH, 1024, 0, stream>>>(loc, tt);

  dim3 ggrid(KVW / BN, (BATCH * TM) / BM);   // (32, 32)
  gemm_f32_kernel<<<ggrid, 256, 0, stream>>>(image, Wkv, kv,
                                             BATCH * TM, KVW, DIM);

  vbar_kernel<<<BATCH * 4, 256, 0, stream>>>(kv, vbar);
  obar_kernel<<<BATCH * 4, 256, 0, stream>>>(vbar, Wo, obar);

  attn_kernel<<<BATCH * NTXT, 256, 0, stream>>>(text, kv, Wq, Wo, gamma, beta,
                                                tt, obar, out);
}

// Round 2
// 269.027 us; speedup vs baseline: 2.1375x; 2.1375x over previous
//
#include <hip/hip_runtime.h>

// Problem constants (setup_inputs is fixed)
#define BATCH 2
#define NTXT  2048
#define TMED  4
#define MMED  256
#define TM    (TMED * MMED)      // 1024 kv rows per batch
#define DIM   1024
#define NH    16
#define DHD   64
#define KVW   2048               // k|v concatenated width
#define RMAX  256                // max real rows per batch handled by fast path
#define RT    32                 // row-tile parallelism for heavy-path kernels

// ---------------------------------------------------------------------------
// K1: inclusive scan of locations -> txt_time, plus segment [start, cnt) of
// "real" rows (1 <= tt <= TMED). tt is nondecreasing so the set is contiguous.
// ---------------------------------------------------------------------------
__global__ __launch_bounds__(1024) void scan_kernel(const int* __restrict__ loc,
                                                    int* __restrict__ tt,
                                                    int* __restrict__ seg) {
  __shared__ int buf[NTXT];
  __shared__ int s_start, s_end;
  const int b = blockIdx.x;
  const int tid = threadIdx.x;
  if (tid == 0) { s_start = NTXT; s_end = NTXT; }
  buf[tid]        = loc[b * NTXT + tid];
  buf[tid + 1024] = loc[b * NTXT + tid + 1024];
  __syncthreads();
  for (int off = 1; off < NTXT; off <<= 1) {
    int a0 = (tid >= off) ? buf[tid - off] : 0;
    int a1 = buf[tid + 1024 - off];
    __syncthreads();
    buf[tid] += a0;
    buf[tid + 1024] += a1;
    __syncthreads();
  }
  const int v0 = buf[tid], v1 = buf[tid + 1024];
  tt[b * NTXT + tid]        = v0;
  tt[b * NTXT + tid + 1024] = v1;
  if (v0 >= 1) atomicMin(&s_start, tid);
  if (v0 >= 5) atomicMin(&s_end, tid);
  if (v1 >= 1) atomicMin(&s_start, tid + 1024);
  if (v1 >= 5) atomicMin(&s_end, tid + 1024);
  __syncthreads();
  if (tid == 0) {
    seg[b * 2]     = s_start;
    seg[b * 2 + 1] = s_end - s_start;   // cnt (>=0 since tt>=5 implies tt>=1)
  }
}

// ---------------------------------------------------------------------------
// K2: fp32 tiled GEMM  C[M,N] = A[M,K] @ B[K,N]   (64x64 tile, BK=16)
// ---------------------------------------------------------------------------
#define BM 64
#define BN 64
#define BK 16
__global__ __launch_bounds__(256) void gemm_f32_kernel(
    const float* __restrict__ A, const float* __restrict__ B,
    float* __restrict__ C, int M, int N, int K) {
  __shared__ float As[BK][BM];
  __shared__ float Bs[BK][BN];
  const int tid = threadIdx.x;
  const int tx = tid & 15;
  const int ty = tid >> 4;
  const int row0 = blockIdx.y * BM;
  const int col0 = blockIdx.x * BN;
  const int am = tid >> 2;
  const int ak = (tid & 3) << 2;
  const int bk = tid >> 4;
  const int bn = (tid & 15) << 2;

  float acc[4][4] = {};
  for (int k0 = 0; k0 < K; k0 += BK) {
    const float4 a4 = *reinterpret_cast<const float4*>(
        &A[(size_t)(row0 + am) * K + k0 + ak]);
    As[ak + 0][am] = a4.x; As[ak + 1][am] = a4.y;
    As[ak + 2][am] = a4.z; As[ak + 3][am] = a4.w;
    const float4 b4 = *reinterpret_cast<const float4*>(
        &B[(size_t)(k0 + bk) * N + col0 + bn]);
    *reinterpret_cast<float4*>(&Bs[bk][bn]) = b4;
    __syncthreads();
#pragma unroll
    for (int kk = 0; kk < BK; kk++) {
      float a[4], b[4];
      *(float4*)a = *(const float4*)&As[kk][ty * 4];
      *(float4*)b = *(const float4*)&Bs[kk][tx * 4];
#pragma unroll
      for (int i = 0; i < 4; i++)
#pragma unroll
        for (int j = 0; j < 4; j++) acc[i][j] += a[i] * b[j];
    }
    __syncthreads();
  }
#pragma unroll
  for (int i = 0; i < 4; i++) {
    float4 v = make_float4(acc[i][0], acc[i][1], acc[i][2], acc[i][3]);
    *reinterpret_cast<float4*>(
        &C[(size_t)(row0 + ty * 4 + i) * N + col0 + tx * 4]) = v;
  }
}

// ---------------------------------------------------------------------------
// K3: vbar[b,c] += partial mean of v[b,j,c]; row-tiled, atomics into vbar.
// grid: (b * 16 coltiles of 64, 8 rowtiles of 128)
// ---------------------------------------------------------------------------
__global__ __launch_bounds__(256) void vbar_kernel(const float* __restrict__ kv,
                                                   float* __restrict__ vbar) {
  const int bc = blockIdx.x;            // b*16 + ctile
  const int b = bc >> 4, ct = bc & 15;
  const int rt = blockIdx.y;            // 0..7, 128 rows each
  const int tid = threadIdx.x;
  const int c = tid & 63, rr = tid >> 6;  // 4 row groups of 32
  __shared__ float part[4][64];
  const float* p = kv + (size_t)(b * TM + rt * 128 + rr * 32) * KVW + DIM + ct * 64 + c;
  float s = 0.f;
#pragma unroll 4
  for (int j = 0; j < 32; j++) s += p[(size_t)j * KVW];
  part[rr][c] = s;
  __syncthreads();
  if (tid < 64)
    atomicAdd(&vbar[b * DIM + ct * 64 + tid],
              (part[0][tid] + part[1][tid] + part[2][tid] + part[3][tid]) *
                  (1.0f / (float)TM));
}

// ---------------------------------------------------------------------------
// K4: obar[b,e] += vbar[b, ctile] @ Wo[ctile, e]; c-tiled, atomics.
// grid: (b * 4 etiles of 256, 8 ctiles of 128)
// ---------------------------------------------------------------------------
__global__ __launch_bounds__(256) void obar_kernel(const float* __restrict__ vbar,
                                                   const float* __restrict__ Wo,
                                                   float* __restrict__ obar) {
  const int be = blockIdx.x;            // b*4 + etile
  const int b = be >> 2, et = be & 3;
  const int ct = blockIdx.y;            // 0..7, 128 c each
  const int tid = threadIdx.x;
  float s = 0.f;
  const float* w = Wo + (size_t)(ct * 128) * DIM + et * 256 + tid;
  const float* vb = vbar + b * DIM + ct * 128;
  for (int c = 0; c < 128; c++) s += vb[c] * w[(size_t)c * DIM];
  atomicAdd(&obar[b * DIM + et * 256 + tid], s);
}

// ---------------------------------------------------------------------------
// K5: fill kernel. One block per (b,i): t==0 -> zero, t>4 -> obar copy,
// real rows -> skip (heavy path) unless r >= RMAX (slow fallback, never hit
// for realistic data but keeps the kernel correct for any input).
// ---------------------------------------------------------------------------
__global__ __launch_bounds__(256) void fill_kernel(
    const float* __restrict__ text, const float* __restrict__ kv,
    const float* __restrict__ Wq, const float* __restrict__ Wo,
    const float* __restrict__ gamma, const float* __restrict__ beta,
    const int* __restrict__ tt, const int* __restrict__ seg,
    const float* __restrict__ obar, float* __restrict__ out) {
  const int tid = threadIdx.x;
  const int b = blockIdx.x >> 11;
  const int i = blockIdx.x & (NTXT - 1);
  const int t = tt[b * NTXT + i];
  float* orow = out + (size_t)(b * NTXT + i) * DIM;

  if (t == 0) {
    for (int c = tid; c < DIM; c += 256) orow[c] = 0.f;
    return;
  }
  if (t > TMED) {
    const float* ob = obar + b * DIM;
    for (int c = tid; c < DIM; c += 256) orow[c] = ob[c];
    return;
  }
  if (i - seg[b * 2] < RMAX) return;   // heavy path covers this row

  // ---- slow fallback (unreachable for realistic inputs) ----
  __shared__ float tn[DIM];
  __shared__ float qrow[DIM];
  __shared__ float oacc[DIM];
  __shared__ float red[256];
  __shared__ float pbuf[256];
  const float* xrow = text + (size_t)(b * NTXT + i) * DIM;
  float x[4];
  float s = 0.f;
#pragma unroll
  for (int u = 0; u < 4; u++) { x[u] = xrow[tid + 256 * u]; s += x[u]; }
  red[tid] = s; __syncthreads();
  for (int st = 128; st > 0; st >>= 1) {
    if (tid < st) red[tid] += red[tid + st];
    __syncthreads();
  }
  const float mu = red[0] * (1.0f / DIM); __syncthreads();
  float vs = 0.f;
#pragma unroll
  for (int u = 0; u < 4; u++) { float d = x[u] - mu; vs += d * d; }
  red[tid] = vs; __syncthreads();
  for (int st = 128; st > 0; st >>= 1) {
    if (tid < st) red[tid] += red[tid + st];
    __syncthreads();
  }
  const float rstd = rsqrtf(red[0] * (1.0f / DIM) + 1e-5f); __syncthreads();
#pragma unroll
  for (int u = 0; u < 4; u++) {
    const int c = tid + 256 * u;
    tn[c] = (x[u] - mu) * rstd * gamma[c] + beta[c];
  }
  __syncthreads();
  {
    float qa[4] = {0.f, 0.f, 0.f, 0.f};
    for (int c = 0; c < DIM; c++) {
      const float tv = tn[c];
      const float* w = Wq + (size_t)c * DIM + tid;
#pragma unroll
      for (int u = 0; u < 4; u++) qa[u] += tv * w[256 * u];
    }
#pragma unroll
    for (int u = 0; u < 4; u++) qrow[tid + 256 * u] = qa[u];
  }
  __syncthreads();
  const size_t kvrow0 = (size_t)(b * TM + (t - 1) * MMED) * KVW;
  const int d0 = tid & 63, g = tid >> 6;
  for (int h = 0; h < NH; h++) {
    const float* krow = kv + kvrow0 + (size_t)tid * KVW + h * DHD;
    float sc = 0.f;
#pragma unroll
    for (int d = 0; d < DHD; d++) sc += qrow[h * DHD + d] * krow[d];
    sc *= 0.125f;
    red[tid] = sc; __syncthreads();
    for (int st = 128; st > 0; st >>= 1) {
      if (tid < st) red[tid] = fmaxf(red[tid], red[tid + st]);
      __syncthreads();
    }
    const float mx = red[0]; __syncthreads();
    const float e = __expf(sc - mx);
    red[tid] = e; __syncthreads();
    for (int st = 128; st > 0; st >>= 1) {
      if (tid < st) red[tid] += red[tid + st];
      __syncthreads();
    }
    const float inv = 1.0f / red[0]; __syncthreads();
    pbuf[tid] = e * inv; __syncthreads();
    const float* vbase = kv + kvrow0 + (size_t)(g * 64) * KVW + DIM + h * DHD + d0;
    float a = 0.f;
#pragma unroll 8
    for (int j = 0; j < 64; j++) a += pbuf[g * 64 + j] * vbase[(size_t)j * KVW];
    red[tid] = a; __syncthreads();
    if (tid < 64)
      oacc[h * DHD + tid] = red[tid] + red[64 + tid] + red[128 + tid] + red[192 + tid];
    __syncthreads();
  }
  float oa[4] = {0.f, 0.f, 0.f, 0.f};
  for (int c = 0; c < DIM; c++) {
    const float ov = oacc[c];
    const float* w = Wo + (size_t)c * DIM + tid;
#pragma unroll
    for (int u = 0; u < 4; u++) oa[u] += ov * w[256 * u];
  }
#pragma unroll
  for (int u = 0; u < 4; u++) orow[tid + 256 * u] = oa[u];
}

// ---------------------------------------------------------------------------
// K6: LayerNorm of real rows -> tn buffer. grid (RT, BATCH)
// ---------------------------------------------------------------------------
__global__ __launch_bounds__(256) void ln_kernel(
    const float* __restrict__ text, const float* __restrict__ gamma,
    const float* __restrict__ beta, const int* __restrict__ seg,
    float* __restrict__ tn) {
  const int rt = blockIdx.x;
  const int b = blockIdx.y;
  const int i0 = seg[b * 2];
  const int cnt = min(seg[b * 2 + 1], RMAX);
  const int tid = threadIdx.x;
  __shared__ float red[256];
  for (int r = rt; r < cnt; r += RT) {
    const float* xrow = text + (size_t)(b * NTXT + i0 + r) * DIM;
    float x[4];
    float s = 0.f;
#pragma unroll
    for (int u = 0; u < 4; u++) { x[u] = xrow[tid + 256 * u]; s += x[u]; }
    red[tid] = s; __syncthreads();
    for (int st = 128; st > 0; st >>= 1) {
      if (tid < st) red[tid] += red[tid + st];
      __syncthreads();
    }
    const float mu = red[0] * (1.0f / DIM); __syncthreads();
    float vs = 0.f;
#pragma unroll
    for (int u = 0; u < 4; u++) { float d = x[u] - mu; vs += d * d; }
    red[tid] = vs; __syncthreads();
    for (int st = 128; st > 0; st >>= 1) {
      if (tid < st) red[tid] += red[tid + st];
      __syncthreads();
    }
    const float rstd = rsqrtf(red[0] * (1.0f / DIM) + 1e-5f); __syncthreads();
    float* trow = tn + (size_t)(b * RMAX + r) * DIM;
#pragma unroll
    for (int u = 0; u < 4; u++) {
      const int c = tid + 256 * u;
      trow[c] = (x[u] - mu) * rstd * gamma[c] + beta[c];
    }
    __syncthreads();
  }
}

// ---------------------------------------------------------------------------
// K7: per-(head,row) attention: q = tn @ Wq[:,h], scores, softmax, PV -> oacc
// grid (NH, RT, BATCH)
// ---------------------------------------------------------------------------
__global__ __launch_bounds__(256) void attnh_kernel(
    const float* __restrict__ tn, const float* __restrict__ kv,
    const float* __restrict__ Wq, const int* __restrict__ tt,
    const int* __restrict__ seg, float* __restrict__ oacc) {
  const int h = blockIdx.x;
  const int rt = blockIdx.y;
  const int b = blockIdx.z;
  const int i0 = seg[b * 2];
  const int cnt = min(seg[b * 2 + 1], RMAX);
  const int tid = threadIdx.x;
  const int d0 = tid & 63, g = tid >> 6;
  __shared__ float q[DHD];
  __shared__ float qp[4][DHD];
  __shared__ float red[256];
  __shared__ float pbuf[256];
  for (int r = rt; r < cnt; r += RT) {
    const int i = i0 + r;
    const int t = tt[b * NTXT + i];         // guaranteed in [1, TMED]
    const float* tnrow = tn + (size_t)(b * RMAX + r) * DIM;
    // q for this head: thread (g, d0) does a quarter of the c-sum
    float qa = 0.f;
    const float* wq = Wq + (size_t)(g * 256) * DIM + h * DHD + d0;
    for (int c = 0; c < 256; c++) qa += tnrow[g * 256 + c] * wq[(size_t)c * DIM];
    qp[g][d0] = qa; __syncthreads();
    if (tid < 64) q[tid] = qp[0][tid] + qp[1][tid] + qp[2][tid] + qp[3][tid];
    __syncthreads();
    // scores: thread <-> kv column j = tid
    const size_t kvrow0 = (size_t)(b * TM + (t - 1) * MMED) * KVW;
    const float* krow = kv + kvrow0 + (size_t)tid * KVW + h * DHD;
    float sc = 0.f;
#pragma unroll
    for (int d = 0; d < DHD; d += 4) {
      const float4 kk = *reinterpret_cast<const float4*>(&krow[d]);
      sc += q[d] * kk.x + q[d + 1] * kk.y + q[d + 2] * kk.z + q[d + 3] * kk.w;
    }
    sc *= 0.125f;
    red[tid] = sc; __syncthreads();
    for (int st = 128; st > 0; st >>= 1) {
      if (tid < st) red[tid] = fmaxf(red[tid], red[tid + st]);
      __syncthreads();
    }
    const float mx = red[0]; __syncthreads();
    const float e = __expf(sc - mx);
    red[tid] = e; __syncthreads();
    for (int st = 128; st > 0; st >>= 1) {
      if (tid < st) red[tid] += red[tid + st];
      __syncthreads();
    }
    const float inv = 1.0f / red[0]; __syncthreads();
    pbuf[tid] = e * inv; __syncthreads();
    // PV
    const float* vbase = kv + kvrow0 + (size_t)(g * 64) * KVW + DIM + h * DHD + d0;
    float a = 0.f;
#pragma unroll 8
    for (int j = 0; j < 64; j++) a += pbuf[g * 64 + j] * vbase[(size_t)j * KVW];
    red[tid] = a; __syncthreads();
    if (tid < 64)
      oacc[(size_t)(b * RMAX + r) * DIM + h * DHD + tid] =
          red[tid] + red[64 + tid] + red[128 + tid] + red[192 + tid];
    __syncthreads();
  }
}

// ---------------------------------------------------------------------------
// K8: output projection for real rows: out[i] = oacc[r] @ Wo (col-tiled)
// grid (16 coltiles of 64, RT, BATCH)
// ---------------------------------------------------------------------------
__global__ __launch_bounds__(256) void oproj_kernel(
    const float* __restrict__ oacc, const float* __restrict__ Wo,
    const int* __restrict__ seg, float* __restrict__ out) {
  const int ct = blockIdx.x;
  const int rt = blockIdx.y;
  const int b = blockIdx.z;
  const int i0 = seg[b * 2];
  const int cnt = min(seg[b * 2 + 1], RMAX);
  const int tid = threadIdx.x;
  const int d0 = tid & 63, g = tid >> 6;
  __shared__ float op[4][64];
  for (int r = rt; r < cnt; r += RT) {
    const float* arow = oacc + (size_t)(b * RMAX + r) * DIM;
    const float* wo = Wo + (size_t)(g * 256) * DIM + ct * 64 + d0;
    float s = 0.f;
    for (int c = 0; c < 256; c++) s += arow[g * 256 + c] * wo[(size_t)c * DIM];
    op[g][d0] = s; __syncthreads();
    if (tid < 64)
      out[(size_t)(b * NTXT + i0 + r) * DIM + ct * 64 + tid] =
          op[0][tid] + op[1][tid] + op[2][tid] + op[3][tid];
    __syncthreads();
  }
}

// ---------------------------------------------------------------------------
extern "C" void kernel_launch(void* const* d_in, const int* in_sizes, int n_in,
                              void* d_out, int out_size, void* d_ws, size_t ws_size,
                              hipStream_t stream) {
  const float* text  = (const float*)d_in[0];
  const float* image = (const float*)d_in[1];
  const int*   loc   = (const int*)d_in[2];
  const float* Wq    = (const float*)d_in[3];
  const float* Wkv   = (const float*)d_in[4];
  const float* Wo    = (const float*)d_in[5];
  const float* gamma = (const float*)d_in[6];
  const float* beta  = (const float*)d_in[7];
  float* out = (float*)d_out;

  // ws layout (floats): kv | tn | oacc | vbar | obar | tt(int) | seg(int)
  float* kv   = (float*)d_ws;
  float* tn   = kv + (size_t)BATCH * TM * KVW;          // 4,194,304
  float* oacc = tn + (size_t)BATCH * RMAX * DIM;        // +524,288
  float* vbar = oacc + (size_t)BATCH * RMAX * DIM;      // +524,288
  float* obar = vbar + BATCH * DIM;                     // +2,048
  int*   tt   = (int*)(obar + BATCH * DIM);             // +2,048
  int*   seg  = tt + BATCH * NTXT;                      // +4,096 ints

  scan_kernel<<<BATCH, 1024, 0, stream>>>(loc, tt, seg);

  dim3 ggrid(KVW / BN, (BATCH * TM) / BM);   // (32, 32)
  gemm_f32_kernel<<<ggrid, 256, 0, stream>>>(image, Wkv, kv,
                                             BATCH * TM, KVW, DIM);

  hipMemsetAsync(vbar, 0, 2 * BATCH * DIM * sizeof(float), stream);  // vbar+obar
  vbar_kernel<<<dim3(BATCH * 16, 8), 256, 0, stream>>>(kv, vbar);
  obar_kernel<<<dim3(BATCH * 4, 8), 256, 0, stream>>>(vbar, Wo, obar);

  fill_kernel<<<BATCH * NTXT, 256, 0, stream>>>(text, kv, Wq, Wo, gamma, beta,
                                                tt, seg, obar, out);
  ln_kernel<<<dim3(RT, BATCH), 256, 0, stream>>>(text, gamma, beta, seg, tn);
  attnh_kernel<<<dim3(NH, RT, BATCH), 256, 0, stream>>>(tn, kv, Wq, tt, seg, oacc);
  oproj_kernel<<<dim3(16, RT, BATCH), 256, 0, stream>>>(oacc, Wo, seg, out);
}

// Round 3
// 178.920 us; speedup vs baseline: 3.2140x; 1.5036x over previous
//
#include <hip/hip_runtime.h>

// Problem constants (setup_inputs is fixed)
#define BATCH 2
#define NTXT  2048
#define TMED  4
#define MMED  256
#define TM    (TMED * MMED)      // 1024 kv rows per batch
#define DIM   1024
#define NH    16
#define DHD   64
#define KVW   2048               // k|v concatenated width
#define RMAX  256                // max real rows per batch handled by fast path
#define RT    32                 // row-tile parallelism for heavy-path kernels

typedef _Float16 f16x8 __attribute__((ext_vector_type(8)));
typedef float    f32x4 __attribute__((ext_vector_type(4)));

// ---------------------------------------------------------------------------
// K1: inclusive scan of locations -> txt_time + real-row segment [start,cnt)
// ---------------------------------------------------------------------------
__global__ __launch_bounds__(1024) void scan_kernel(const int* __restrict__ loc,
                                                    int* __restrict__ tt,
                                                    int* __restrict__ seg) {
  __shared__ int buf[NTXT];
  __shared__ int s_start, s_end;
  const int b = blockIdx.x;
  const int tid = threadIdx.x;
  if (tid == 0) { s_start = NTXT; s_end = NTXT; }
  buf[tid]        = loc[b * NTXT + tid];
  buf[tid + 1024] = loc[b * NTXT + tid + 1024];
  __syncthreads();
  for (int off = 1; off < NTXT; off <<= 1) {
    int a0 = (tid >= off) ? buf[tid - off] : 0;
    int a1 = buf[tid + 1024 - off];
    __syncthreads();
    buf[tid] += a0;
    buf[tid + 1024] += a1;
    __syncthreads();
  }
  const int v0 = buf[tid], v1 = buf[tid + 1024];
  tt[b * NTXT + tid]        = v0;
  tt[b * NTXT + tid + 1024] = v1;
  if (v0 >= 1) atomicMin(&s_start, tid);
  if (v0 >= 5) atomicMin(&s_end, tid);
  if (v1 >= 1) atomicMin(&s_start, tid + 1024);
  if (v1 >= 5) atomicMin(&s_end, tid + 1024);
  __syncthreads();
  if (tid == 0) {
    seg[b * 2]     = s_start;
    seg[b * 2 + 1] = s_end - s_start;
  }
}

// ---------------------------------------------------------------------------
// K2: Wkv (K x N fp32) -> WkvT (N x K fp16), 64x64 LDS tile transpose
// grid: 512 blocks (16 k-tiles x 32 n-tiles)
// ---------------------------------------------------------------------------
__global__ __launch_bounds__(256) void convert_kernel(const float* __restrict__ Wkv,
                                                      _Float16* __restrict__ Bt) {
  const int tb = blockIdx.x;
  const int k0 = (tb & 15) * 64, n0 = (tb >> 4) * 64;
  __shared__ float tile[64][65];
  const int tid = threadIdx.x;
  const int r = tid >> 4, c4 = (tid & 15) * 4;
#pragma unroll
  for (int i = 0; i < 4; i++) {
    const float4 v = *reinterpret_cast<const float4*>(
        Wkv + (size_t)(k0 + r + i * 16) * KVW + n0 + c4);
    tile[r + i * 16][c4 + 0] = v.x; tile[r + i * 16][c4 + 1] = v.y;
    tile[r + i * 16][c4 + 2] = v.z; tile[r + i * 16][c4 + 3] = v.w;
  }
  __syncthreads();
#pragma unroll
  for (int it = 0; it < 2; it++) {
    const int chunk = it * 256 + tid;
    const int n = chunk >> 3, kc = (chunk & 7) * 8;
    f16x8 h;
#pragma unroll
    for (int j = 0; j < 8; j++) h[j] = (_Float16)tile[kc + j][n];
    *reinterpret_cast<f16x8*>(Bt + (size_t)(n0 + n) * DIM + k0 + kc) = h;
  }
}

// ---------------------------------------------------------------------------
// K3: fp16 MFMA GEMM  kv[M,N] = image[M,K] @ WkvT[N,K]^T  + fused vbar
// 128x128 tile, BK=32, 512 threads (8 waves: 4 row-waves x 2 col-waves)
// ---------------------------------------------------------------------------
__global__ __launch_bounds__(512) void gemm_f16_kernel(
    const float* __restrict__ A, const _Float16* __restrict__ Bt,
    float* __restrict__ C, float* __restrict__ vbar) {
  const int M = BATCH * TM, N = KVW, K = DIM;
  (void)M;
  __shared__ _Float16 As[128 * 32];
  __shared__ _Float16 Bs[128 * 32];
  const int tid = threadIdx.x;
  const int lane = tid & 63, wid = tid >> 6;
  const int wm = wid & 3, wn = wid >> 2;       // wave rows [wm*32), cols [wn*64)
  const int row0 = blockIdx.y * 128, col0 = blockIdx.x * 128;
  const int srow = tid >> 2, skc = (tid & 3) * 8;  // staging row / k-chunk
  const int frow = lane & 15, fq = lane >> 4;      // fragment row, quad

  f32x4 acc[2][4] = {};

  for (int k0 = 0; k0 < K; k0 += 32) {
    // stage A (fp32 -> fp16 in-register) and B (fp16 direct)
    const float* ap = A + (size_t)(row0 + srow) * K + k0 + skc;
    const float4 a0 = *reinterpret_cast<const float4*>(ap);
    const float4 a1 = *reinterpret_cast<const float4*>(ap + 4);
    f16x8 av;
    av[0] = (_Float16)a0.x; av[1] = (_Float16)a0.y;
    av[2] = (_Float16)a0.z; av[3] = (_Float16)a0.w;
    av[4] = (_Float16)a1.x; av[5] = (_Float16)a1.y;
    av[6] = (_Float16)a1.z; av[7] = (_Float16)a1.w;
    const f16x8 bv = *reinterpret_cast<const f16x8*>(
        Bt + (size_t)(col0 + srow) * K + k0 + skc);
    __syncthreads();
    *reinterpret_cast<f16x8*>(As + tid * 8) = av;   // [row][k] : tid*8
    *reinterpret_cast<f16x8*>(Bs + tid * 8) = bv;
    __syncthreads();

    f16x8 af[2], bf[4];
#pragma unroll
    for (int mt = 0; mt < 2; mt++)
      af[mt] = *reinterpret_cast<const f16x8*>(
          As + (wm * 32 + mt * 16 + frow) * 32 + fq * 8);
#pragma unroll
    for (int nt = 0; nt < 4; nt++)
      bf[nt] = *reinterpret_cast<const f16x8*>(
          Bs + (wn * 64 + nt * 16 + frow) * 32 + fq * 8);
#pragma unroll
    for (int mt = 0; mt < 2; mt++)
#pragma unroll
      for (int nt = 0; nt < 4; nt++)
        acc[mt][nt] = __builtin_amdgcn_mfma_f32_16x16x32_f16(
            af[mt], bf[nt], acc[mt][nt], 0, 0, 0);
  }

  // C write (C/D layout: col = lane&15, row = quad*4 + reg)
#pragma unroll
  for (int mt = 0; mt < 2; mt++)
#pragma unroll
    for (int nt = 0; nt < 4; nt++) {
      const int col = col0 + wn * 64 + nt * 16 + frow;
#pragma unroll
      for (int r = 0; r < 4; r++) {
        const int row = row0 + wm * 32 + mt * 16 + fq * 4 + r;
        C[(size_t)row * N + col] = acc[mt][nt][r];
      }
    }

  // fused vbar: column sums of the v-half, shuffle-reduced, atomics
  if (col0 >= DIM) {
    const int b = row0 >> 10;
#pragma unroll
    for (int nt = 0; nt < 4; nt++) {
      float s = 0.f;
#pragma unroll
      for (int mt = 0; mt < 2; mt++)
#pragma unroll
        for (int r = 0; r < 4; r++) s += acc[mt][nt][r];
      s += __shfl_down(s, 32);
      s += __shfl_down(s, 16);
      if (lane < 16)
        atomicAdd(&vbar[b * DIM + (col0 - DIM) + wn * 64 + nt * 16 + lane],
                  s * (1.0f / (float)TM));
    }
  }
}

// ---------------------------------------------------------------------------
// K4: obar[b,e] += vbar[b, ctile] @ Wo[ctile, e]; c-tiled, atomics.
// ---------------------------------------------------------------------------
__global__ __launch_bounds__(256) void obar_kernel(const float* __restrict__ vbar,
                                                   const float* __restrict__ Wo,
                                                   float* __restrict__ obar) {
  const int be = blockIdx.x;
  const int b = be >> 2, et = be & 3;
  const int ct = blockIdx.y;
  const int tid = threadIdx.x;
  float s = 0.f;
  const float* w = Wo + (size_t)(ct * 128) * DIM + et * 256 + tid;
  const float* vb = vbar + b * DIM + ct * 128;
  for (int c = 0; c < 128; c++) s += vb[c] * w[(size_t)c * DIM];
  atomicAdd(&obar[b * DIM + et * 256 + tid], s);
}

// ---------------------------------------------------------------------------
// K5: fill kernel: t==0 -> zero, t>4 -> obar, real rows -> skip (heavy path)
// unless r >= RMAX (slow fallback; unreachable for realistic data).
// ---------------------------------------------------------------------------
__global__ __launch_bounds__(256) void fill_kernel(
    const float* __restrict__ text, const float* __restrict__ kv,
    const float* __restrict__ Wq, const float* __restrict__ Wo,
    const float* __restrict__ gamma, const float* __restrict__ beta,
    const int* __restrict__ tt, const int* __restrict__ seg,
    const float* __restrict__ obar, float* __restrict__ out) {
  const int tid = threadIdx.x;
  const int b = blockIdx.x >> 11;
  const int i = blockIdx.x & (NTXT - 1);
  const int t = tt[b * NTXT + i];
  float* orow = out + (size_t)(b * NTXT + i) * DIM;

  if (t == 0) {
    for (int c = tid; c < DIM; c += 256) orow[c] = 0.f;
    return;
  }
  if (t > TMED) {
    const float* ob = obar + b * DIM;
    for (int c = tid; c < DIM; c += 256) orow[c] = ob[c];
    return;
  }
  if (i - seg[b * 2] < RMAX) return;

  // ---- slow fallback ----
  __shared__ float tn[DIM];
  __shared__ float qrow[DIM];
  __shared__ float oaccs[DIM];
  __shared__ float red[256];
  __shared__ float pbuf[256];
  const float* xrow = text + (size_t)(b * NTXT + i) * DIM;
  float x[4];
  float s = 0.f;
#pragma unroll
  for (int u = 0; u < 4; u++) { x[u] = xrow[tid + 256 * u]; s += x[u]; }
  red[tid] = s; __syncthreads();
  for (int st = 128; st > 0; st >>= 1) {
    if (tid < st) red[tid] += red[tid + st];
    __syncthreads();
  }
  const float mu = red[0] * (1.0f / DIM); __syncthreads();
  float vs = 0.f;
#pragma unroll
  for (int u = 0; u < 4; u++) { float d = x[u] - mu; vs += d * d; }
  red[tid] = vs; __syncthreads();
  for (int st = 128; st > 0; st >>= 1) {
    if (tid < st) red[tid] += red[tid + st];
    __syncthreads();
  }
  const float rstd = rsqrtf(red[0] * (1.0f / DIM) + 1e-5f); __syncthreads();
#pragma unroll
  for (int u = 0; u < 4; u++) {
    const int c = tid + 256 * u;
    tn[c] = (x[u] - mu) * rstd * gamma[c] + beta[c];
  }
  __syncthreads();
  {
    float qa[4] = {0.f, 0.f, 0.f, 0.f};
    for (int c = 0; c < DIM; c++) {
      const float tv = tn[c];
      const float* w = Wq + (size_t)c * DIM + tid;
#pragma unroll
      for (int u = 0; u < 4; u++) qa[u] += tv * w[256 * u];
    }
#pragma unroll
    for (int u = 0; u < 4; u++) qrow[tid + 256 * u] = qa[u];
  }
  __syncthreads();
  const size_t kvrow0 = (size_t)(b * TM + (t - 1) * MMED) * KVW;
  const int d0 = tid & 63, g = tid >> 6;
  for (int h = 0; h < NH; h++) {
    const float* krow = kv + kvrow0 + (size_t)tid * KVW + h * DHD;
    float sc = 0.f;
#pragma unroll
    for (int d = 0; d < DHD; d++) sc += qrow[h * DHD + d] * krow[d];
    sc *= 0.125f;
    red[tid] = sc; __syncthreads();
    for (int st = 128; st > 0; st >>= 1) {
      if (tid < st) red[tid] = fmaxf(red[tid], red[tid + st]);
      __syncthreads();
    }
    const float mx = red[0]; __syncthreads();
    const float e = __expf(sc - mx);
    red[tid] = e; __syncthreads();
    for (int st = 128; st > 0; st >>= 1) {
      if (tid < st) red[tid] += red[tid + st];
      __syncthreads();
    }
    const float inv = 1.0f / red[0]; __syncthreads();
    pbuf[tid] = e * inv; __syncthreads();
    const float* vbase = kv + kvrow0 + (size_t)(g * 64) * KVW + DIM + h * DHD + d0;
    float a = 0.f;
#pragma unroll 8
    for (int j = 0; j < 64; j++) a += pbuf[g * 64 + j] * vbase[(size_t)j * KVW];
    red[tid] = a; __syncthreads();
    if (tid < 64)
      oaccs[h * DHD + tid] = red[tid] + red[64 + tid] + red[128 + tid] + red[192 + tid];
    __syncthreads();
  }
  float oa[4] = {0.f, 0.f, 0.f, 0.f};
  for (int c = 0; c < DIM; c++) {
    const float ov = oaccs[c];
    const float* w = Wo + (size_t)c * DIM + tid;
#pragma unroll
    for (int u = 0; u < 4; u++) oa[u] += ov * w[256 * u];
  }
#pragma unroll
  for (int u = 0; u < 4; u++) orow[tid + 256 * u] = oa[u];
}

// ---------------------------------------------------------------------------
// K6: per-(head,row) attention with inline LayerNorm. grid (NH, RT, BATCH)
// ---------------------------------------------------------------------------
__global__ __launch_bounds__(256) void attnh_kernel(
    const float* __restrict__ text, const float* __restrict__ kv,
    const float* __restrict__ Wq, const float* __restrict__ gamma,
    const float* __restrict__ beta, const int* __restrict__ tt,
    const int* __restrict__ seg, float* __restrict__ oacc) {
  const int h = blockIdx.x;
  const int rt = blockIdx.y;
  const int b = blockIdx.z;
  const int i0 = seg[b * 2];
  const int cnt = min(seg[b * 2 + 1], RMAX);
  const int tid = threadIdx.x;
  const int d0 = tid & 63, g = tid >> 6;
  __shared__ float tn_s[DIM];
  __shared__ float q[DHD];
  __shared__ float qp[4][DHD];
  __shared__ float red[256];
  __shared__ float pbuf[256];
  for (int r = rt; r < cnt; r += RT) {
    const int i = i0 + r;
    const int t = tt[b * NTXT + i];         // in [1, TMED]
    // --- LayerNorm (redundant per head; ~4 KB read, trivial) ---
    const float* xrow = text + (size_t)(b * NTXT + i) * DIM;
    float x[4];
    float s = 0.f;
#pragma unroll
    for (int u = 0; u < 4; u++) { x[u] = xrow[tid + 256 * u]; s += x[u]; }
    red[tid] = s; __syncthreads();
    for (int st = 128; st > 0; st >>= 1) {
      if (tid < st) red[tid] += red[tid + st];
      __syncthreads();
    }
    const float mu = red[0] * (1.0f / DIM); __syncthreads();
    float vs = 0.f;
#pragma unroll
    for (int u = 0; u < 4; u++) { float d = x[u] - mu; vs += d * d; }
    red[tid] = vs; __syncthreads();
    for (int st = 128; st > 0; st >>= 1) {
      if (tid < st) red[tid] += red[tid + st];
      __syncthreads();
    }
    const float rstd = rsqrtf(red[0] * (1.0f / DIM) + 1e-5f); __syncthreads();
#pragma unroll
    for (int u = 0; u < 4; u++) {
      const int c = tid + 256 * u;
      tn_s[c] = (x[u] - mu) * rstd * gamma[c] + beta[c];
    }
    __syncthreads();
    // --- q for this head ---
    float qa = 0.f;
    const float* wq = Wq + (size_t)(g * 256) * DIM + h * DHD + d0;
    for (int c = 0; c < 256; c++) qa += tn_s[g * 256 + c] * wq[(size_t)c * DIM];
    qp[g][d0] = qa; __syncthreads();
    if (tid < 64) q[tid] = qp[0][tid] + qp[1][tid] + qp[2][tid] + qp[3][tid];
    __syncthreads();
    // --- scores + softmax ---
    const size_t kvrow0 = (size_t)(b * TM + (t - 1) * MMED) * KVW;
    const float* krow = kv + kvrow0 + (size_t)tid * KVW + h * DHD;
    float sc = 0.f;
#pragma unroll
    for (int d = 0; d < DHD; d += 4) {
      const float4 kk = *reinterpret_cast<const float4*>(&krow[d]);
      sc += q[d] * kk.x + q[d + 1] * kk.y + q[d + 2] * kk.z + q[d + 3] * kk.w;
    }
    sc *= 0.125f;
    red[tid] = sc; __syncthreads();
    for (int st = 128; st > 0; st >>= 1) {
      if (tid < st) red[tid] = fmaxf(red[tid], red[tid + st]);
      __syncthreads();
    }
    const float mx = red[0]; __syncthreads();
    const float e = __expf(sc - mx);
    red[tid] = e; __syncthreads();
    for (int st = 128; st > 0; st >>= 1) {
      if (tid < st) red[tid] += red[tid + st];
      __syncthreads();
    }
    const float inv = 1.0f / red[0]; __syncthreads();
    pbuf[tid] = e * inv; __syncthreads();
    // --- PV ---
    const float* vbase = kv + kvrow0 + (size_t)(g * 64) * KVW + DIM + h * DHD + d0;
    float a = 0.f;
#pragma unroll 8
    for (int j = 0; j < 64; j++) a += pbuf[g * 64 + j] * vbase[(size_t)j * KVW];
    red[tid] = a; __syncthreads();
    if (tid < 64)
      oacc[(size_t)(b * RMAX + r) * DIM + h * DHD + tid] =
          red[tid] + red[64 + tid] + red[128 + tid] + red[192 + tid];
    __syncthreads();
  }
}

// ---------------------------------------------------------------------------
// K7: output projection for real rows. grid (16, RT, BATCH)
// ---------------------------------------------------------------------------
__global__ __launch_bounds__(256) void oproj_kernel(
    const float* __restrict__ oacc, const float* __restrict__ Wo,
    const int* __restrict__ seg, float* __restrict__ out) {
  const int ct = blockIdx.x;
  const int rt = blockIdx.y;
  const int b = blockIdx.z;
  const int i0 = seg[b * 2];
  const int cnt = min(seg[b * 2 + 1], RMAX);
  const int tid = threadIdx.x;
  const int d0 = tid & 63, g = tid >> 6;
  __shared__ float op[4][64];
  for (int r = rt; r < cnt; r += RT) {
    const float* arow = oacc + (size_t)(b * RMAX + r) * DIM;
    const float* wo = Wo + (size_t)(g * 256) * DIM + ct * 64 + d0;
    float s = 0.f;
    for (int c = 0; c < 256; c++) s += arow[g * 256 + c] * wo[(size_t)c * DIM];
    op[g][d0] = s; __syncthreads();
    if (tid < 64)
      out[(size_t)(b * NTXT + i0 + r) * DIM + ct * 64 + tid] =
          op[0][tid] + op[1][tid] + op[2][tid] + op[3][tid];
    __syncthreads();
  }
}

// ---------------------------------------------------------------------------
extern "C" void kernel_launch(void* const* d_in, const int* in_sizes, int n_in,
                              void* d_out, int out_size, void* d_ws, size_t ws_size,
                              hipStream_t stream) {
  const float* text  = (const float*)d_in[0];
  const float* image = (const float*)d_in[1];
  const int*   loc   = (const int*)d_in[2];
  const float* Wq    = (const float*)d_in[3];
  const float* Wkv   = (const float*)d_in[4];
  const float* Wo    = (const float*)d_in[5];
  const float* gamma = (const float*)d_in[6];
  const float* beta  = (const float*)d_in[7];
  float* out = (float*)d_out;

  // ws layout: kv (16 MB f32) | WkvT (4 MB f16, aliased by oacc 2 MB f32
  // after gemm is done with it) | vbar | obar | tt | seg   (~21 MB total)
  float*    kv   = (float*)d_ws;
  _Float16* WkvT = (_Float16*)(kv + (size_t)BATCH * TM * KVW);
  float*    oacc = (float*)WkvT;                       // alias: attnh > gemm
  float*    vbar = (float*)(WkvT + (size_t)KVW * DIM);
  float*    obar = vbar + BATCH * DIM;
  int*      tt   = (int*)(obar + BATCH * DIM);
  int*      seg  = tt + BATCH * NTXT;

  scan_kernel<<<BATCH, 1024, 0, stream>>>(loc, tt, seg);
  convert_kernel<<<512, 256, 0, stream>>>(Wkv, WkvT);
  hipMemsetAsync(vbar, 0, 2 * BATCH * DIM * sizeof(float), stream);

  dim3 ggrid(KVW / 128, (BATCH * TM) / 128);   // (16, 16)
  gemm_f16_kernel<<<ggrid, 512, 0, stream>>>(image, WkvT, kv, vbar);

  obar_kernel<<<dim3(BATCH * 4, 8), 256, 0, stream>>>(vbar, Wo, obar);
  fill_kernel<<<BATCH * NTXT, 256, 0, stream>>>(text, kv, Wq, Wo, gamma, beta,
                                                tt, seg, obar, out);
  attnh_kernel<<<dim3(NH, RT, BATCH), 256, 0, stream>>>(text, kv, Wq, gamma,
                                                        beta, tt, seg, oacc);
  oproj_kernel<<<dim3(16, RT, BATCH), 256, 0, stream>>>(oacc, Wo, seg, out);
}